// Round 10
// baseline (153.984 us; speedup 1.0000x reference)
//
#include <hip/hip_runtime.h>
#include <hip/hip_fp16.h>
#include <math.h>

#define NN 100000
#define NE 1600000
#define DIM 64
#define HST 72   // proj LDS stride in halves (144B, 16B-aligned rows)
#define PROJ_BLOCKS ((2 * NN) / 64)          // 3125
#define ROWPTR_BLOCKS ((NE + 255) / 256)     // 6250

typedef __attribute__((ext_vector_type(8))) __fp16 half8;
typedef __attribute__((ext_vector_type(4))) float f32x4;
typedef __attribute__((ext_vector_type(4))) unsigned u32x4;

__device__ __forceinline__ __half2 u2h2(unsigned u) { __half2 h; __builtin_memcpy(&h, &u, 4); return h; }
__device__ __forceinline__ unsigned h22u(__half2 h) { unsigned u; __builtin_memcpy(&u, &h, 4); return u; }
__device__ __forceinline__ unsigned pk_f16(float a, float b) {
    auto h = __builtin_amdgcn_cvt_pkrtz(a, b);   // one v_cvt_pkrtz_f16_f32
    unsigned u; __builtin_memcpy(&u, &h, 4); return u;
}

// ---------------------------------------------------------------------------
// Kernel 1 (fused): blocks [0,PROJ_BLOCKS) do the MFMA projection
// p = h @ W^T (f16, f32-acc) + a = p.w_attn; blocks [PROJ_BLOCKS, ...) do the
// CSR row_ptr boundary scan (independent; overlaps the compute-bound proj).
// h loads are non-temporal (read exactly once) to avoid polluting L2/L3;
// p16 stores stay cached (read by agg in the same iteration).
// ---------------------------------------------------------------------------
__global__ __launch_bounds__(256) void proj_kernel(
    const float* __restrict__ h_src, const float* __restrict__ h_dst,
    const float* __restrict__ W, const float* __restrict__ w_attn,
    const int* __restrict__ dst, int* __restrict__ row_ptr,
    unsigned* __restrict__ p16, float* __restrict__ a_src, float* __restrict__ a_dst) {
    __shared__ __align__(16) unsigned short Hh[64 * HST];  // f16 bits
    __shared__ __align__(16) unsigned short Wh[64 * HST];
    __shared__ float was[DIM];

    const int t = threadIdx.x;

    if (blockIdx.x >= PROJ_BLOCKS) {
        // ---- rowptr part: boundary scan over sorted dst ----
        int i = (blockIdx.x - PROJ_BLOCKS) * 256 + t;
        if (i >= NE) return;
        int d = dst[i];
        int prev = (i == 0) ? -1 : dst[i - 1];
        for (int n = prev + 1; n <= d; ++n) row_ptr[n] = i;
        if (i == NE - 1) {
            for (int n = d + 1; n <= NN; ++n) row_ptr[n] = NE;
        }
        return;
    }

    const int row0 = blockIdx.x * 64;

    // Stage W (f32 -> f16): cached (hot across all 3125 blocks).
#pragma unroll
    for (int r = 0; r < 4; ++r) {
        int idx = (r * 256 + t) * 4;           // flat float index into 64x64 W
        int j = idx >> 6, k = idx & 63;
        float4 v = *(const float4*)(W + idx);
        uint2 pk; pk.x = pk_f16(v.x, v.y); pk.y = pk_f16(v.z, v.w);
        *(uint2*)((char*)Wh + j * (HST * 2) + k * 2) = pk;
    }
    if (t < DIM) was[t] = w_attn[t];

    // Stage H tile (row-major, no transpose). Non-temporal: read exactly once.
#pragma unroll
    for (int r = 0; r < 4; ++r) {
        int idx = (r * 256 + t) * 4;
        int row = idx >> 6, k = idx & 63;
        int grow = row0 + row;
        const float* hp = (grow < NN) ? h_src + (size_t)grow * DIM
                                      : h_dst + (size_t)(grow - NN) * DIM;
        f32x4 v = __builtin_nontemporal_load((const f32x4*)(hp + k));
        uint2 pk; pk.x = pk_f16(v.x, v.y); pk.y = pk_f16(v.z, v.w);
        *(uint2*)((char*)Hh + row * (HST * 2) + k * 2) = pk;
    }
    __syncthreads();

    const int wv = t >> 6, lane = t & 63;
    const int col = lane & 15, quad = lane >> 4;
    const int m0 = wv * 16;

    const char* Hb = (const char*)Hh + (m0 + col) * (HST * 2) + quad * 16;
    half8 af0 = *(const half8*)(Hb);           // k = quad*8+j, k0=0
    half8 af1 = *(const half8*)(Hb + 64);      // k0=32

    f32x4 c[4];
#pragma unroll
    for (int n = 0; n < 4; ++n) {
        const char* Bb = (const char*)Wh + (n * 16 + col) * (HST * 2) + quad * 16;
        half8 b0 = *(const half8*)(Bb);
        half8 b1 = *(const half8*)(Bb + 64);
        f32x4 acc = {0.f, 0.f, 0.f, 0.f};
        acc = __builtin_amdgcn_mfma_f32_16x16x32_f16(af0, b0, acc, 0, 0, 0);
        acc = __builtin_amdgcn_mfma_f32_16x16x32_f16(af1, b1, acc, 0, 0, 0);
        c[n] = acc;
    }

    // a = p . w_attn : per-lane partial over its 4 cols, reduce 16 cols in group.
    float wv4[4];
#pragma unroll
    for (int n = 0; n < 4; ++n) wv4[n] = was[n * 16 + col];
#pragma unroll
    for (int reg = 0; reg < 4; ++reg) {
        float pa = c[0][reg] * wv4[0] + c[1][reg] * wv4[1] +
                   c[2][reg] * wv4[2] + c[3][reg] * wv4[3];
#pragma unroll
        for (int off = 1; off <= 8; off <<= 1) pa += __shfl_xor(pa, off);
        if (col == 0) {
            int grow = row0 + m0 + quad * 4 + reg;
            if (grow < NN) a_src[grow] = pa;
            else a_dst[grow - NN] = pa;
        }
    }

    // Pack p to f16 dwords via LDS repack, then fully-coalesced dwordx4 store.
    __syncthreads();
    unsigned* Pd = (unsigned*)Hh;              // reuse: 64 rows x 32 dwords
#pragma unroll
    for (int n = 0; n < 4; ++n) {
#pragma unroll
        for (int reg = 0; reg < 4; ++reg) {
            float other = __shfl_xor(c[n][reg], 1);
            if (!(col & 1)) {
                unsigned pk = pk_f16(c[n][reg], other);
                Pd[(m0 + quad * 4 + reg) * 32 + (n * 16 + col) / 2] = pk;
            }
        }
    }
    __syncthreads();
#pragma unroll
    for (int r = 0; r < 2; ++r) {
        int idx = (r * 256 + t) * 4;           // dword index into 2048-dword tile
        uint4 v = *(const uint4*)(Pd + idx);
        *(uint4*)(p16 + (size_t)row0 * 32 + idx) = v;   // cached: agg reads it next
    }
}

// ---------------------------------------------------------------------------
// Kernel 2: fused edge-score + segment softmax + aggregation + ELU.
// Quarter-wave per node (16 lanes/node, 4 nodes/wave, 16/block).
// Stream-once traffic (src loads, out stores) is non-temporal so the L2/L3
// keep the randomly-gathered p_src rows (the only reused data) resident.
// h_diff[n] = p_dst[n] - (sum_e w_e * p_src[src_e]) / s   (sum alpha = 1)
// ---------------------------------------------------------------------------
__global__ __launch_bounds__(256) void agg_kernel(
    const char* __restrict__ p16base,    // rows of 128B f16; [0,NN)=src, [NN,2NN)=dst
    const float* __restrict__ a_src, const float* __restrict__ a_dst,
    const int* __restrict__ src, const int* __restrict__ row_ptr,
    float* __restrict__ out) {
    __shared__ uint2 buf[4][64];
    const int wv = threadIdx.x >> 6;
    const int lane = threadIdx.x & 63;
    const int g = lane >> 4;            // group (node) within wave
    const int glane = lane & 15;        // lane within group
    const int sub16 = glane >> 3;       // which edge of a pair
    const int chunk = glane & 7;        // which 16B chunk of the 128B row

    const int wid = (blockIdx.x * 4 + wv) * 4 + g;
    if (wid >= NN) return;

    const int beg = row_ptr[wid];
    const int end = row_ptr[wid + 1];
    const bool nonempty = end > beg;

    f32x4 zero = {0.f, 0.f, 0.f, 0.f};
    float* obase = out + (size_t)wid * DIM + chunk * 8;

    if (!nonempty) {
        if (sub16 == 0) {
            __builtin_nontemporal_store(zero, (f32x4*)obase);
            __builtin_nontemporal_store(zero, (f32x4*)(obase + 4));
        }
        return;
    }

    // prefetch p_dst row chunk early (only the lanes that consume it)
    u32x4 pdu = {0u, 0u, 0u, 0u};
    if (sub16 == 0)
        pdu = *(const u32x4*)(p16base + ((size_t)(NN + wid)) * 128 + (size_t)chunk * 16);

    const float ad = a_dst[wid];
    const char* pbase = p16base + (size_t)chunk * 16;
    uint2* bufw = buf[wv];
    const int gbase = g * 16;

    float sAcc = 0.f;
    __half2 acc[4];
#pragma unroll
    for (int q = 0; q < 4; ++q) acc[q] = u2h2(0u);

    for (int cb = beg; cb < end; cb += 16) {
        int cd = end - cb; if (cd > 16) cd = 16;
        uint2 pk = make_uint2(0u, 0u);
        float w = 0.f;
        if (glane < cd) {
            int sv = __builtin_nontemporal_load(src + cb + glane);  // stream-once
            float x = ad - a_src[sv];                  // 4B gather, L2-resident
            float th = 1.f - 2.f / (__expf(2.f * x) + 1.f);   // tanh
            w = __expf(th);
            pk.x = pk_f16(w, w);
            pk.y = (unsigned)sv * 128u;                // pre-scaled byte offset
        }
        sAcc += w;
        bufw[lane] = pk;                               // wave-private, no barrier

        if (cd == 16) {
            // fast path: 8 gathers in flight per lane (16 edges/group)
            uint2 e[8];
#pragma unroll
            for (int q = 0; q < 8; ++q) e[q] = bufw[gbase + 2 * q + sub16];
            uint4 r[8];
#pragma unroll
            for (int q = 0; q < 8; ++q) r[q] = *(const uint4*)(pbase + e[q].y);
#pragma unroll
            for (int q = 0; q < 8; ++q) {
                __half2 wq = u2h2(e[q].x);
                acc[0] = __hfma2(wq, u2h2(r[q].x), acc[0]);
                acc[1] = __hfma2(wq, u2h2(r[q].y), acc[1]);
                acc[2] = __hfma2(wq, u2h2(r[q].z), acc[2]);
                acc[3] = __hfma2(wq, u2h2(r[q].w), acc[3]);
            }
        } else {
            for (int j = 0; j < cd; j += 4) {          // 4 edges/group/iter
                uint2 e0 = bufw[gbase + j + sub16];
                uint2 e1 = bufw[gbase + j + 2 + sub16];    // zero-filled beyond cd
                uint4 r0 = *(const uint4*)(pbase + e0.y);
                uint4 r1 = *(const uint4*)(pbase + e1.y);
                __half2 w0 = u2h2(e0.x), w1 = u2h2(e1.x);
                acc[0] = __hfma2(w0, u2h2(r0.x), acc[0]);
                acc[1] = __hfma2(w0, u2h2(r0.y), acc[1]);
                acc[2] = __hfma2(w0, u2h2(r0.z), acc[2]);
                acc[3] = __hfma2(w0, u2h2(r0.w), acc[3]);
                acc[0] = __hfma2(w1, u2h2(r1.x), acc[0]);
                acc[1] = __hfma2(w1, u2h2(r1.y), acc[1]);
                acc[2] = __hfma2(w1, u2h2(r1.z), acc[2]);
                acc[3] = __hfma2(w1, u2h2(r1.w), acc[3]);
            }
        }
    }

#pragma unroll
    for (int off = 1; off <= 8; off <<= 1) sAcc += __shfl_xor(sAcc, off);
#pragma unroll
    for (int q = 0; q < 4; ++q)
        acc[q] = __hadd2(acc[q], u2h2(__shfl_xor(h22u(acc[q]), 8)));

    if (sub16 == 0) {   // 8 lanes per group write the node's 64 channels
        const unsigned pw[4] = {pdu.x, pdu.y, pdu.z, pdu.w};
        const float inv = 1.f / sAcc;
        f32x4 o0, o1;
#pragma unroll
        for (int q = 0; q < 4; ++q) {
            float2 pf = __half22float2(u2h2(pw[q]));
            float2 af = __half22float2(acc[q]);
            float h0 = pf.x - af.x * inv;
            float h1 = pf.y - af.y * inv;
            float v0 = h0 > 0.f ? h0 : __expf(h0) - 1.f;
            float v1 = h1 > 0.f ? h1 : __expf(h1) - 1.f;
            if (q < 2) { o0[2 * q] = v0; o0[2 * q + 1] = v1; }
            else       { o1[2 * (q - 2)] = v0; o1[2 * (q - 2) + 1] = v1; }
        }
        __builtin_nontemporal_store(o0, (f32x4*)obase);       // stream-once out
        __builtin_nontemporal_store(o1, (f32x4*)(obase + 4));
    }
}

// ---------------------------------------------------------------------------
extern "C" void kernel_launch(void* const* d_in, const int* in_sizes, int n_in,
                              void* d_out, int out_size, void* d_ws, size_t ws_size,
                              hipStream_t stream) {
    const float* h_src = (const float*)d_in[0];
    const float* h_dst = (const float*)d_in[1];
    const float* W     = (const float*)d_in[2];
    const float* w_at  = (const float*)d_in[3];
    const int*   src   = (const int*)d_in[4];
    const int*   dst   = (const int*)d_in[5];

    char* ws = (char*)d_ws;
    unsigned* p16 = (unsigned*)ws;                        // 2NN*32 dwords = 25.6 MB
    float* a_src = (float*)(ws + (size_t)2 * NN * 32 * 4);
    float* a_dst = a_src + NN;
    int* row_ptr = (int*)(a_dst + NN);                    // NN+1

    hipLaunchKernelGGL(proj_kernel, dim3(PROJ_BLOCKS + ROWPTR_BLOCKS), dim3(256), 0, stream,
                       h_src, h_dst, W, w_at, dst, row_ptr, p16, a_src, a_dst);
    hipLaunchKernelGGL(agg_kernel, dim3((NN + 15) / 16), dim3(256), 0, stream,
                       (const char*)p16, a_src, a_dst, src, row_ptr,
                       (float*)d_out);
}

// Round 11
// 147.960 us; speedup vs baseline: 1.0407x; 1.0407x over previous
//
#include <hip/hip_runtime.h>
#include <hip/hip_fp16.h>
#include <math.h>

#define NN 100000
#define NE 1600000
#define DIM 64
#define HST 72   // proj LDS stride in halves (144B, 16B-aligned rows)
#define PROJ_BLOCKS ((2 * NN) / 64)          // 3125
#define ROWPTR_BLOCKS ((NE + 255) / 256)     // 6250

typedef __attribute__((ext_vector_type(8))) __fp16 half8;
typedef __attribute__((ext_vector_type(4))) float f32x4;

__device__ __forceinline__ __half2 u2h2(unsigned u) { __half2 h; __builtin_memcpy(&h, &u, 4); return h; }
__device__ __forceinline__ unsigned h22u(__half2 h) { unsigned u; __builtin_memcpy(&u, &h, 4); return u; }
__device__ __forceinline__ unsigned pk_f16(float a, float b) {
    auto h = __builtin_amdgcn_cvt_pkrtz(a, b);   // one v_cvt_pkrtz_f16_f32
    unsigned u; __builtin_memcpy(&u, &h, 4); return u;
}

// ---------------------------------------------------------------------------
// Kernel 1 (fused): blocks [0,PROJ_BLOCKS) do the MFMA projection
// p = h @ W^T (f16, f32-acc) + a = p.w_attn; blocks [PROJ_BLOCKS, +ROWPTR_BLOCKS)
// do the CSR row_ptr boundary scan. The two halves are independent (agg needs
// both) — fusing overlaps the BW-bound scan with the compute-bound proj.
// NOTE (R10 post-mortem): non-temporal hints on h/src/out REGRESSED (+4.3 µs
// total; agg occupancy 72->53%, VGPR 28->36, LDS conflicts 0->409K). Keep
// all accesses default-cached.
// ---------------------------------------------------------------------------
__global__ __launch_bounds__(256) void proj_kernel(
    const float* __restrict__ h_src, const float* __restrict__ h_dst,
    const float* __restrict__ W, const float* __restrict__ w_attn,
    const int* __restrict__ dst, int* __restrict__ row_ptr,
    unsigned* __restrict__ p16, float* __restrict__ a_src, float* __restrict__ a_dst) {
    __shared__ __align__(16) unsigned short Hh[64 * HST];  // f16 bits
    __shared__ __align__(16) unsigned short Wh[64 * HST];
    __shared__ float was[DIM];

    const int t = threadIdx.x;

    if (blockIdx.x >= PROJ_BLOCKS) {
        // ---- rowptr part: boundary scan over sorted dst ----
        int i = (blockIdx.x - PROJ_BLOCKS) * 256 + t;
        if (i >= NE) return;
        int d = dst[i];
        int prev = (i == 0) ? -1 : dst[i - 1];
        for (int n = prev + 1; n <= d; ++n) row_ptr[n] = i;
        if (i == NE - 1) {
            for (int n = d + 1; n <= NN; ++n) row_ptr[n] = NE;
        }
        return;
    }

    const int row0 = blockIdx.x * 64;

    // Stage W (f32 -> f16), coalesced float4 reads, contiguous 8B LDS writes.
#pragma unroll
    for (int r = 0; r < 4; ++r) {
        int idx = (r * 256 + t) * 4;           // flat float index into 64x64 W
        int j = idx >> 6, k = idx & 63;
        float4 v = *(const float4*)(W + idx);
        uint2 pk; pk.x = pk_f16(v.x, v.y); pk.y = pk_f16(v.z, v.w);
        *(uint2*)((char*)Wh + j * (HST * 2) + k * 2) = pk;
    }
    if (t < DIM) was[t] = w_attn[t];

    // Stage H tile (row-major, no transpose).
#pragma unroll
    for (int r = 0; r < 4; ++r) {
        int idx = (r * 256 + t) * 4;
        int row = idx >> 6, k = idx & 63;
        int grow = row0 + row;
        const float* hp = (grow < NN) ? h_src + (size_t)grow * DIM
                                      : h_dst + (size_t)(grow - NN) * DIM;
        float4 v = *(const float4*)(hp + k);
        uint2 pk; pk.x = pk_f16(v.x, v.y); pk.y = pk_f16(v.z, v.w);
        *(uint2*)((char*)Hh + row * (HST * 2) + k * 2) = pk;
    }
    __syncthreads();

    const int wv = t >> 6, lane = t & 63;
    const int col = lane & 15, quad = lane >> 4;
    const int m0 = wv * 16;

    const char* Hb = (const char*)Hh + (m0 + col) * (HST * 2) + quad * 16;
    half8 af0 = *(const half8*)(Hb);           // k = quad*8+j, k0=0
    half8 af1 = *(const half8*)(Hb + 64);      // k0=32

    f32x4 c[4];
#pragma unroll
    for (int n = 0; n < 4; ++n) {
        const char* Bb = (const char*)Wh + (n * 16 + col) * (HST * 2) + quad * 16;
        half8 b0 = *(const half8*)(Bb);
        half8 b1 = *(const half8*)(Bb + 64);
        f32x4 acc = {0.f, 0.f, 0.f, 0.f};
        acc = __builtin_amdgcn_mfma_f32_16x16x32_f16(af0, b0, acc, 0, 0, 0);
        acc = __builtin_amdgcn_mfma_f32_16x16x32_f16(af1, b1, acc, 0, 0, 0);
        c[n] = acc;
    }

    // a = p . w_attn : per-lane partial over its 4 cols, reduce 16 cols in group.
    float wv4[4];
#pragma unroll
    for (int n = 0; n < 4; ++n) wv4[n] = was[n * 16 + col];
#pragma unroll
    for (int reg = 0; reg < 4; ++reg) {
        float pa = c[0][reg] * wv4[0] + c[1][reg] * wv4[1] +
                   c[2][reg] * wv4[2] + c[3][reg] * wv4[3];
#pragma unroll
        for (int off = 1; off <= 8; off <<= 1) pa += __shfl_xor(pa, off);
        if (col == 0) {
            int grow = row0 + m0 + quad * 4 + reg;
            if (grow < NN) a_src[grow] = pa;
            else a_dst[grow - NN] = pa;
        }
    }

    // Pack p to f16 dwords via LDS repack, then fully-coalesced dwordx4 store.
    __syncthreads();
    unsigned* Pd = (unsigned*)Hh;              // reuse: 64 rows x 32 dwords
#pragma unroll
    for (int n = 0; n < 4; ++n) {
#pragma unroll
        for (int reg = 0; reg < 4; ++reg) {
            float other = __shfl_xor(c[n][reg], 1);
            if (!(col & 1)) {
                unsigned pk = pk_f16(c[n][reg], other);
                Pd[(m0 + quad * 4 + reg) * 32 + (n * 16 + col) / 2] = pk;
            }
        }
    }
    __syncthreads();
#pragma unroll
    for (int r = 0; r < 2; ++r) {
        int idx = (r * 256 + t) * 4;           // dword index into 2048-dword tile
        uint4 v = *(const uint4*)(Pd + idx);
        *(uint4*)(p16 + (size_t)row0 * 32 + idx) = v;
    }
}

// ---------------------------------------------------------------------------
// Kernel 2: fused edge-score + segment softmax + aggregation + ELU.
// Quarter-wave per node (16 lanes/node, 4 nodes/wave, 16/block).
// Fast path for full 16-edge chunks: 8 LDS entry reads then 8 independent
// dwordx4 gathers in flight (4x the MLP of the 2-deep loop).
// h_diff[n] = p_dst[n] - (sum_e w_e * p_src[src_e]) / s   (sum alpha = 1)
// ---------------------------------------------------------------------------
__global__ __launch_bounds__(256) void agg_kernel(
    const char* __restrict__ p16base,    // rows of 128B f16; [0,NN)=src, [NN,2NN)=dst
    const float* __restrict__ a_src, const float* __restrict__ a_dst,
    const int* __restrict__ src, const int* __restrict__ row_ptr,
    float4* __restrict__ out4) {
    __shared__ uint2 buf[4][64];
    const int wv = threadIdx.x >> 6;
    const int lane = threadIdx.x & 63;
    const int g = lane >> 4;            // group (node) within wave
    const int glane = lane & 15;        // lane within group
    const int sub16 = glane >> 3;       // which edge of a pair
    const int chunk = glane & 7;        // which 16B chunk of the 128B row

    const int wid = (blockIdx.x * 4 + wv) * 4 + g;
    if (wid >= NN) return;

    const int beg = row_ptr[wid];
    const int end = row_ptr[wid + 1];
    const bool nonempty = end > beg;

    if (!nonempty) {
        if (sub16 == 0) {
            const size_t ob = (size_t)wid * 16 + chunk * 2;
            out4[ob]     = make_float4(0.f, 0.f, 0.f, 0.f);
            out4[ob + 1] = make_float4(0.f, 0.f, 0.f, 0.f);
        }
        return;
    }

    // prefetch p_dst row chunk early (overlaps the edge loop)
    const uint4 pdu = *(const uint4*)(p16base + ((size_t)(NN + wid)) * 128 + (size_t)chunk * 16);

    const float ad = a_dst[wid];
    const char* pbase = p16base + (size_t)chunk * 16;
    uint2* bufw = buf[wv];
    const int gbase = g * 16;

    float sAcc = 0.f;
    __half2 acc[4];
#pragma unroll
    for (int q = 0; q < 4; ++q) acc[q] = u2h2(0u);

    for (int cb = beg; cb < end; cb += 16) {
        int cd = end - cb; if (cd > 16) cd = 16;
        uint2 pk = make_uint2(0u, 0u);
        float w = 0.f;
        if (glane < cd) {
            int sv = src[cb + glane];                  // ~coalesced
            float x = ad - a_src[sv];                  // 4B gather, L2-resident
            float th = 1.f - 2.f / (__expf(2.f * x) + 1.f);   // tanh
            w = __expf(th);
            pk.x = pk_f16(w, w);
            pk.y = (unsigned)sv * 128u;                // pre-scaled byte offset
        }
        sAcc += w;
        bufw[lane] = pk;                               // wave-private, no barrier

        if (cd == 16) {
            // fast path: 8 gathers in flight per lane (16 edges/group)
            uint2 e[8];
#pragma unroll
            for (int q = 0; q < 8; ++q) e[q] = bufw[gbase + 2 * q + sub16];
            uint4 r[8];
#pragma unroll
            for (int q = 0; q < 8; ++q) r[q] = *(const uint4*)(pbase + e[q].y);
#pragma unroll
            for (int q = 0; q < 8; ++q) {
                __half2 wq = u2h2(e[q].x);
                acc[0] = __hfma2(wq, u2h2(r[q].x), acc[0]);
                acc[1] = __hfma2(wq, u2h2(r[q].y), acc[1]);
                acc[2] = __hfma2(wq, u2h2(r[q].z), acc[2]);
                acc[3] = __hfma2(wq, u2h2(r[q].w), acc[3]);
            }
        } else {
            for (int j = 0; j < cd; j += 4) {          // 4 edges/group/iter
                uint2 e0 = bufw[gbase + j + sub16];
                uint2 e1 = bufw[gbase + j + 2 + sub16];    // zero-filled beyond cd
                uint4 r0 = *(const uint4*)(pbase + e0.y);
                uint4 r1 = *(const uint4*)(pbase + e1.y);
                __half2 w0 = u2h2(e0.x), w1 = u2h2(e1.x);
                acc[0] = __hfma2(w0, u2h2(r0.x), acc[0]);
                acc[1] = __hfma2(w0, u2h2(r0.y), acc[1]);
                acc[2] = __hfma2(w0, u2h2(r0.z), acc[2]);
                acc[3] = __hfma2(w0, u2h2(r0.w), acc[3]);
                acc[0] = __hfma2(w1, u2h2(r1.x), acc[0]);
                acc[1] = __hfma2(w1, u2h2(r1.y), acc[1]);
                acc[2] = __hfma2(w1, u2h2(r1.z), acc[2]);
                acc[3] = __hfma2(w1, u2h2(r1.w), acc[3]);
            }
        }
    }

#pragma unroll
    for (int off = 1; off <= 8; off <<= 1) sAcc += __shfl_xor(sAcc, off);
#pragma unroll
    for (int q = 0; q < 4; ++q)
        acc[q] = __hadd2(acc[q], u2h2(__shfl_xor(h22u(acc[q]), 8)));

    if (sub16 == 0) {   // 8 lanes per group write the node's 64 channels
        const unsigned pw[4] = {pdu.x, pdu.y, pdu.z, pdu.w};
        const float inv = 1.f / sAcc;
        float o[8];
#pragma unroll
        for (int q = 0; q < 4; ++q) {
            float2 pf = __half22float2(u2h2(pw[q]));
            float2 af = __half22float2(acc[q]);
            float h0 = pf.x - af.x * inv;
            float h1 = pf.y - af.y * inv;
            o[2 * q]     = h0 > 0.f ? h0 : __expf(h0) - 1.f;
            o[2 * q + 1] = h1 > 0.f ? h1 : __expf(h1) - 1.f;
        }
        const size_t ob = (size_t)wid * 16 + chunk * 2;
        out4[ob]     = make_float4(o[0], o[1], o[2], o[3]);
        out4[ob + 1] = make_float4(o[4], o[5], o[6], o[7]);
    }
}

// ---------------------------------------------------------------------------
extern "C" void kernel_launch(void* const* d_in, const int* in_sizes, int n_in,
                              void* d_out, int out_size, void* d_ws, size_t ws_size,
                              hipStream_t stream) {
    const float* h_src = (const float*)d_in[0];
    const float* h_dst = (const float*)d_in[1];
    const float* W     = (const float*)d_in[2];
    const float* w_at  = (const float*)d_in[3];
    const int*   src   = (const int*)d_in[4];
    const int*   dst   = (const int*)d_in[5];

    char* ws = (char*)d_ws;
    unsigned* p16 = (unsigned*)ws;                        // 2NN*32 dwords = 25.6 MB
    float* a_src = (float*)(ws + (size_t)2 * NN * 32 * 4);
    float* a_dst = a_src + NN;
    int* row_ptr = (int*)(a_dst + NN);                    // NN+1

    hipLaunchKernelGGL(proj_kernel, dim3(PROJ_BLOCKS + ROWPTR_BLOCKS), dim3(256), 0, stream,
                       h_src, h_dst, W, w_at, dst, row_ptr, p16, a_src, a_dst);
    hipLaunchKernelGGL(agg_kernel, dim3((NN + 15) / 16), dim3(256), 0, stream,
                       (const char*)p16, a_src, a_dst, src, row_ptr,
                       (float4*)d_out);
}